// Round 2
// baseline (598.421 us; speedup 1.0000x reference)
//
#include <hip/hip_runtime.h>
#include <stdint.h>

typedef unsigned short u16;
typedef __attribute__((ext_vector_type(8))) short s16x8;
typedef __attribute__((ext_vector_type(4))) float f32x4;

// ---------- helpers ----------
__device__ __forceinline__ u16 f2bf(float f) {
  uint32_t u = __float_as_uint(f);
  uint32_t r = (u + 0x7FFFu + ((u >> 16) & 1u)) >> 16;   // RNE
  return (u16)r;
}

__device__ __forceinline__ void gll16(const void* g, void* lds) {
  __builtin_amdgcn_global_load_lds(
      (const __attribute__((address_space(1))) uint32_t*)g,
      (__attribute__((address_space(3))) uint32_t*)lds, 16, 0, 0);
}

// ---------- fp32 -> bf16 weight convert ----------
__global__ __launch_bounds__(256) void k_f2b(const float* __restrict__ src,
                                             u16* __restrict__ dst, int n) {
  int i = (blockIdx.x * 256 + threadIdx.x) * 4;
  if (i < n) {
    float4 v = *(const float4*)(src + i);
    ushort4 o;
    o.x = f2bf(v.x); o.y = f2bf(v.y); o.z = f2bf(v.z); o.w = f2bf(v.w);
    *(ushort4*)(dst + i) = o;
  }
}

// ---------- fused residual-mix + RMSNorm ----------
template <bool MIX>
__global__ __launch_bounds__(256) void k_rms(const float* __restrict__ X,
                                             const float* __restrict__ X0,
                                             const float* __restrict__ rmix,
                                             float* __restrict__ XMout,
                                             u16* __restrict__ Hout, float eps) {
  const int row = blockIdx.x, t = threadIdx.x;
  const size_t base = (size_t)row * 1024;
  float4 v;
  if (MIX) {
    float4 a = ((const float4*)(X + base))[t];
    float4 b = ((const float4*)(X0 + base))[t];
    float4 c0 = ((const float4*)rmix)[t];
    float4 c1 = ((const float4*)(rmix + 1024))[t];
    v.x = c0.x * a.x + c1.x * b.x;
    v.y = c0.y * a.y + c1.y * b.y;
    v.z = c0.z * a.z + c1.z * b.z;
    v.w = c0.w * a.w + c1.w * b.w;
  } else {
    v = ((const float4*)(X + base))[t];
  }
  float ss = v.x * v.x + v.y * v.y + v.z * v.z + v.w * v.w;
#pragma unroll
  for (int o = 32; o > 0; o >>= 1) ss += __shfl_xor(ss, o);
  __shared__ float red[4];
  if ((t & 63) == 0) red[t >> 6] = ss;
  __syncthreads();
  float tot = red[0] + red[1] + red[2] + red[3];
  float sc = rsqrtf(tot * (1.0f / 1024.0f) + eps);
  if (MIX) ((float4*)(XMout + base))[t] = v;
  ushort4 hv;
  hv.x = f2bf(v.x * sc); hv.y = f2bf(v.y * sc);
  hv.z = f2bf(v.z * sc); hv.w = f2bf(v.w * sc);
  ((ushort4*)(Hout + base))[t] = hv;
}

// ---------- RMSNorm of memory/denom -> bf16 m ----------
__global__ __launch_bounds__(256) void k_rms_mem(const float* __restrict__ Mem,
                                                 u16* __restrict__ Mout) {
  const int row = blockIdx.x, t = threadIdx.x;
  const float inv = 1.0f / (float)((row & 4095) + 1);   // S = 4096
  const size_t base = (size_t)row * 1024;
  float4 v = ((const float4*)(Mem + base))[t];
  v.x *= inv; v.y *= inv; v.z *= inv; v.w *= inv;
  float ss = v.x * v.x + v.y * v.y + v.z * v.z + v.w * v.w;
#pragma unroll
  for (int o = 32; o > 0; o >>= 1) ss += __shfl_xor(ss, o);
  __shared__ float red[4];
  if ((t & 63) == 0) red[t >> 6] = ss;
  __syncthreads();
  float tot = red[0] + red[1] + red[2] + red[3];
  float sc = rsqrtf(tot * (1.0f / 1024.0f) + 1.1920929e-7f);
  ushort4 hv;
  hv.x = f2bf(v.x * sc); hv.y = f2bf(v.y * sc);
  hv.z = f2bf(v.z * sc); hv.w = f2bf(v.w * sc);
  ((ushort4*)(Mout + base))[t] = hv;
}

// ---------- chunked scan over S ----------
__global__ __launch_bounds__(256) void k_scan1(const float* __restrict__ P,
                                               float* __restrict__ CS) {
  int blk = blockIdx.x;
  int kt = blk & 3, chunk = (blk >> 2) & 15, b = blk >> 6;
  int k = kt * 256 + threadIdx.x;
  const float* p = P + ((size_t)b * 4096 + (size_t)chunk * 256) * 1024 + k;
  float s = 0.f;
#pragma unroll 8
  for (int i = 0; i < 256; ++i) s += p[(size_t)i * 1024];
  CS[((size_t)b * 16 + chunk) * 1024 + k] = s;
}

__global__ __launch_bounds__(256) void k_scan2(float* __restrict__ CS) {
  int idx = blockIdx.x * 256 + threadIdx.x;  // 4096 columns
  int b = idx >> 10, k = idx & 1023;
  float run = 0.f;
  for (int c = 0; c < 16; ++c) {
    size_t o = ((size_t)b * 16 + c) * 1024 + k;
    float v = CS[o];
    CS[o] = run;       // exclusive prefix
    run += v;
  }
}

__global__ __launch_bounds__(256) void k_scan3(float* __restrict__ P,
                                               const float* __restrict__ CS) {
  int blk = blockIdx.x;
  int kt = blk & 3, chunk = (blk >> 2) & 15, b = blk >> 6;
  int k = kt * 256 + threadIdx.x;
  float run = CS[((size_t)b * 16 + chunk) * 1024 + k];
  float* p = P + ((size_t)b * 4096 + (size_t)chunk * 256) * 1024 + k;
#pragma unroll 8
  for (int i = 0; i < 256; ++i) {
    run += p[(size_t)i * 1024];
    p[(size_t)i * 1024] = run;   // in-place: P becomes memory
  }
}

// ---------- dual-B GEMM: P = sigmoid(A@Wg^T) * (A@Wu^T) ----------
// BM=128, BN=64 (per B matrix), BK=64. 4 waves, each 32x64.
__global__ __launch_bounds__(256, 2) void gemm_dual(
    const u16* __restrict__ A, const u16* __restrict__ Bu,
    const u16* __restrict__ Bg, float* __restrict__ P, int K) {
  __shared__ __align__(16) u16 As[128 * 64];
  __shared__ __align__(16) u16 Us[64 * 64];
  __shared__ __align__(16) u16 Gs[64 * 64];
  const int t = threadIdx.x;
  const int lane = t & 63, wid = t >> 6;
  const int m0 = blockIdx.y * 128, n0 = blockIdx.x * 64;
  const int wm = wid * 32;
  const int l15 = lane & 15, lhi = lane >> 4;

  size_t gA[4], gU[2], gG[2];
#pragma unroll
  for (int i = 0; i < 4; ++i) {
    int j = i * 256 + t;
    int row = j >> 3;
    int k16 = (j & 7) ^ (row & 7);
    gA[i] = (size_t)(m0 + row) * K + k16 * 8;
  }
#pragma unroll
  for (int i = 0; i < 2; ++i) {
    int j = i * 256 + t;
    int row = j >> 3;
    int k16 = (j & 7) ^ (row & 7);
    gU[i] = (size_t)(n0 + row) * K + k16 * 8;
    gG[i] = gU[i];
  }

  f32x4 au[2][4], ag[2][4];
#pragma unroll
  for (int mi = 0; mi < 2; ++mi)
#pragma unroll
    for (int ni = 0; ni < 4; ++ni) { au[mi][ni] = 0.0f; ag[mi][ni] = 0.0f; }

  for (int kb = 0; kb < K; kb += 64) {
#pragma unroll
    for (int i = 0; i < 4; ++i) {
      int j = i * 256 + t;
      gll16(A + gA[i] + kb, &As[j * 8]);
    }
#pragma unroll
    for (int i = 0; i < 2; ++i) {
      int j = i * 256 + t;
      gll16(Bu + gU[i] + kb, &Us[j * 8]);
      gll16(Bg + gG[i] + kb, &Gs[j * 8]);
    }
    __syncthreads();
#pragma unroll
    for (int kc = 0; kc < 2; ++kc) {
      s16x8 af[2], uf[4], gf[4];
#pragma unroll
      for (int mi = 0; mi < 2; ++mi) {
        int row = wm + mi * 16 + l15;
        int k16 = (kc * 4 + lhi) ^ (row & 7);
        af[mi] = *(const s16x8*)&As[row * 64 + k16 * 8];
      }
#pragma unroll
      for (int ni = 0; ni < 4; ++ni) {
        int row = ni * 16 + l15;
        int k16 = (kc * 4 + lhi) ^ (row & 7);
        uf[ni] = *(const s16x8*)&Us[row * 64 + k16 * 8];
        gf[ni] = *(const s16x8*)&Gs[row * 64 + k16 * 8];
      }
#pragma unroll
      for (int mi = 0; mi < 2; ++mi)
#pragma unroll
        for (int ni = 0; ni < 4; ++ni) {
          au[mi][ni] = __builtin_amdgcn_mfma_f32_16x16x32_bf16(
              af[mi], uf[ni], au[mi][ni], 0, 0, 0);
          ag[mi][ni] = __builtin_amdgcn_mfma_f32_16x16x32_bf16(
              af[mi], gf[ni], ag[mi][ni], 0, 0, 0);
        }
    }
    __syncthreads();
  }

#pragma unroll
  for (int mi = 0; mi < 2; ++mi) {
    int r0 = m0 + wm + mi * 16 + lhi * 4;
#pragma unroll
    for (int ni = 0; ni < 4; ++ni) {
      int c = n0 + ni * 16 + l15;
#pragma unroll
      for (int j = 0; j < 4; ++j) {
        float u = au[mi][ni][j], g = ag[mi][ni][j];
        P[(size_t)(r0 + j) * 1024 + c] = u / (1.0f + __expf(-g));
      }
    }
  }
}

// ---------- bf16 MFMA GEMM: C[M,N](+ldc) = A[M,K](lda) @ B[N,K](ldb)^T ----------
// EPI 1: Cout(f32) = Cadd + colscale[c]*acc    (in-place Cadd==Cout ok)
// EPI 2: Cout(bf16) = relu(acc)^2
template <int EPI>
__global__ __launch_bounds__(256, 2) void gemm_bf16(
    const u16* __restrict__ A, const u16* __restrict__ Bw, void* __restrict__ Cout,
    const float* __restrict__ Cadd, const float* __restrict__ colscale,
    int K, int lda, int ldb, int ldc) {
  __shared__ __align__(16) u16 As[128 * 64];
  __shared__ __align__(16) u16 Bs[128 * 64];
  const int t = threadIdx.x;
  const int lane = t & 63, wid = t >> 6;
  const int m0 = blockIdx.y * 128, n0 = blockIdx.x * 128;
  const int wm = (wid >> 1) * 64, wn = (wid & 1) * 64;
  const int l15 = lane & 15, lhi = lane >> 4;

  size_t gA[4], gB[4];
#pragma unroll
  for (int i = 0; i < 4; ++i) {
    int j = i * 256 + t;
    int row = j >> 3;
    int k16 = (j & 7) ^ (row & 7);
    gA[i] = (size_t)(m0 + row) * lda + k16 * 8;
    gB[i] = (size_t)(n0 + row) * ldb + k16 * 8;
  }

  f32x4 acc[4][4];
#pragma unroll
  for (int mi = 0; mi < 4; ++mi)
#pragma unroll
    for (int ni = 0; ni < 4; ++ni) acc[mi][ni] = 0.0f;

  for (int kb = 0; kb < K; kb += 64) {
#pragma unroll
    for (int i = 0; i < 4; ++i) {
      int j = i * 256 + t;
      gll16(A + gA[i] + kb, &As[j * 8]);
      gll16(Bw + gB[i] + kb, &Bs[j * 8]);
    }
    __syncthreads();
#pragma unroll
    for (int kc = 0; kc < 2; ++kc) {
      s16x8 af[4], bfr[4];
#pragma unroll
      for (int mi = 0; mi < 4; ++mi) {
        int row = wm + mi * 16 + l15;
        int k16 = (kc * 4 + lhi) ^ (row & 7);
        af[mi] = *(const s16x8*)&As[row * 64 + k16 * 8];
      }
#pragma unroll
      for (int ni = 0; ni < 4; ++ni) {
        int row = wn + ni * 16 + l15;
        int k16 = (kc * 4 + lhi) ^ (row & 7);
        bfr[ni] = *(const s16x8*)&Bs[row * 64 + k16 * 8];
      }
#pragma unroll
      for (int mi = 0; mi < 4; ++mi)
#pragma unroll
        for (int ni = 0; ni < 4; ++ni)
          acc[mi][ni] = __builtin_amdgcn_mfma_f32_16x16x32_bf16(
              af[mi], bfr[ni], acc[mi][ni], 0, 0, 0);
    }
    __syncthreads();
  }

#pragma unroll
  for (int mi = 0; mi < 4; ++mi) {
    int r0 = m0 + wm + mi * 16 + lhi * 4;
#pragma unroll
    for (int ni = 0; ni < 4; ++ni) {
      int c = n0 + wn + ni * 16 + l15;
      float cs = (EPI == 1) ? colscale[c] : 0.f;
#pragma unroll
      for (int j = 0; j < 4; ++j) {
        size_t idx = (size_t)(r0 + j) * ldc + c;
        float v = acc[mi][ni][j];
        if (EPI == 1) {
          ((float*)Cout)[idx] = Cadd[idx] + cs * v;
        } else {
          float rv = fmaxf(v, 0.f);
          ((u16*)Cout)[idx] = f2bf(rv * rv);
        }
      }
    }
  }
}

// ---------- launch ----------
extern "C" void kernel_launch(void* const* d_in, const int* in_sizes, int n_in,
                              void* d_out, int out_size, void* d_ws, size_t ws_size,
                              hipStream_t stream) {
  const float* x = (const float*)d_in[0];
  const float* x0 = (const float*)d_in[1];
  const float* Wu = (const float*)d_in[2];
  const float* Wg = (const float*)d_in[3];
  const float* Wo = (const float*)d_in[4];
  const float* Wfc = (const float*)d_in[5];
  const float* Wpj = (const float*)d_in[6];
  const float* mmix = (const float*)d_in[7];
  const float* mscale = (const float*)d_in[8];
  const float* rmix = (const float*)d_in[9];
  float* out = (float*)d_out;

  const int M = 16384;  // B*S

  // workspace layout (~150.25 MB)
  char* ws = (char*)d_ws;
  u16* WuB = (u16*)ws;   ws += (size_t)1024 * 1024 * 2;
  u16* WgB = (u16*)ws;   ws += (size_t)1024 * 1024 * 2;
  u16* WoB = (u16*)ws;   ws += (size_t)1024 * 1024 * 2;
  u16* WfcB = (u16*)ws;  ws += (size_t)4096 * 1024 * 2;
  u16* WpjB = (u16*)ws;  ws += (size_t)1024 * 4096 * 2;
  u16* h = (u16*)ws;     ws += (size_t)M * 1024 * 2;       // h then h2
  float* P = (float*)ws; u16* R2 = (u16*)P;                // R2 reuses dead P/CS/mB
  ws += (size_t)M * 1024 * 4;                              // P (p -> memory)
  float* CS = (float*)ws; ws += (size_t)4 * 16 * 1024 * 4; // chunk sums
  u16* mB = (u16*)ws;     ws += (size_t)M * 1024 * 2;      // normalized memory
  float* xm = out;                                          // xm/x2 lives in d_out

  // weights -> bf16
  k_f2b<<<1024, 256, 0, stream>>>(Wu, WuB, 1024 * 1024);
  k_f2b<<<1024, 256, 0, stream>>>(Wg, WgB, 1024 * 1024);
  k_f2b<<<1024, 256, 0, stream>>>(Wo, WoB, 1024 * 1024);
  k_f2b<<<4096, 256, 0, stream>>>(Wfc, WfcB, 4096 * 1024);
  k_f2b<<<4096, 256, 0, stream>>>(Wpj, WpjB, 4096 * 1024);

  // residual mix + rmsnorm: xm (=out), h
  k_rms<true><<<M, 256, 0, stream>>>(x, x0, rmix, xm, h, 1e-6f);

  // p = sigmoid(h@Wg^T) * (h@Wu^T)
  gemm_dual<<<dim3(16, 128), 256, 0, stream>>>(h, WuB, WgB, P, 1024);

  // memory = cumsum_S(p)  (3-phase chunked scan, in-place)
  k_scan1<<<256, 256, 0, stream>>>(P, CS);
  k_scan2<<<16, 256, 0, stream>>>(CS);
  k_scan3<<<256, 256, 0, stream>>>(P, CS);

  // m = bf16(rmsnorm(memory/denom))
  k_rms_mem<<<M, 256, 0, stream>>>(P, mB);

  // x2 = xm + mmix * (m @ Wo^T)   (in-place in d_out)
  gemm_bf16<1><<<dim3(8, 128), 256, 0, stream>>>(mB, WoB, xm, xm, mmix,
                                                 1024, 1024, 1024, 1024);
  // h2 = bf16(rmsnorm(x2))
  k_rms<false><<<M, 256, 0, stream>>>(xm, nullptr, nullptr, nullptr, h, 1e-6f);

  // MLP in two HID halves; R2 buffer (M x 2048 bf16) reused
  for (int c = 0; c < 2; ++c) {
    gemm_bf16<2><<<dim3(16, 128), 256, 0, stream>>>(
        h, WfcB + (size_t)c * 2048 * 1024, R2, nullptr, nullptr,
        1024, 1024, 1024, 2048);
    gemm_bf16<1><<<dim3(8, 128), 256, 0, stream>>>(
        R2, WpjB + (size_t)c * 2048, out, out, mscale,
        2048, 2048, 4096, 1024);
  }
}

// Round 3
// 551.336 us; speedup vs baseline: 1.0854x; 1.0854x over previous
//
#include <hip/hip_runtime.h>
#include <stdint.h>

typedef unsigned short u16;
typedef __attribute__((ext_vector_type(8))) short s16x8;
typedef __attribute__((ext_vector_type(4))) float f32x4;

// ---------- helpers ----------
__device__ __forceinline__ u16 f2bf(float f) {
  uint32_t u = __float_as_uint(f);
  uint32_t r = (u + 0x7FFFu + ((u >> 16) & 1u)) >> 16;   // RNE
  return (u16)r;
}

__device__ __forceinline__ void gll16(const void* g, void* lds) {
  __builtin_amdgcn_global_load_lds(
      (const __attribute__((address_space(1))) uint32_t*)g,
      (__attribute__((address_space(3))) uint32_t*)lds, 16, 0, 0);
}

// XCD-aware bijective swizzle: HW assigns linear block id round-robin to the
// 8 XCDs; remap so each XCD owns a CONTIGUOUS chunk of the x-fastest tile
// order -> A-row panels are reused within one XCD's L2. nwg % 8 == 0 for all
// our grids.
__device__ __forceinline__ void xcd_swz(int& bx, int& by) {
  int gx = gridDim.x;
  int lin = blockIdx.y * gx + blockIdx.x;
  int cpx = (gx * gridDim.y) >> 3;
  int nl = (lin & 7) * cpx + (lin >> 3);
  bx = nl % gx;
  by = nl / gx;
}

// ---------- fp32 -> bf16 weight convert ----------
__global__ __launch_bounds__(256) void k_f2b(const float* __restrict__ src,
                                             u16* __restrict__ dst, int n) {
  int i = (blockIdx.x * 256 + threadIdx.x) * 4;
  if (i < n) {
    float4 v = *(const float4*)(src + i);
    ushort4 o;
    o.x = f2bf(v.x); o.y = f2bf(v.y); o.z = f2bf(v.z); o.w = f2bf(v.w);
    *(ushort4*)(dst + i) = o;
  }
}

// ---------- fused residual-mix + RMSNorm ----------
template <bool MIX>
__global__ __launch_bounds__(256) void k_rms(const float* __restrict__ X,
                                             const float* __restrict__ X0,
                                             const float* __restrict__ rmix,
                                             float* __restrict__ XMout,
                                             u16* __restrict__ Hout, float eps) {
  const int row = blockIdx.x, t = threadIdx.x;
  const size_t base = (size_t)row * 1024;
  float4 v;
  if (MIX) {
    float4 a = ((const float4*)(X + base))[t];
    float4 b = ((const float4*)(X0 + base))[t];
    float4 c0 = ((const float4*)rmix)[t];
    float4 c1 = ((const float4*)(rmix + 1024))[t];
    v.x = c0.x * a.x + c1.x * b.x;
    v.y = c0.y * a.y + c1.y * b.y;
    v.z = c0.z * a.z + c1.z * b.z;
    v.w = c0.w * a.w + c1.w * b.w;
  } else {
    v = ((const float4*)(X + base))[t];
  }
  float ss = v.x * v.x + v.y * v.y + v.z * v.z + v.w * v.w;
#pragma unroll
  for (int o = 32; o > 0; o >>= 1) ss += __shfl_xor(ss, o);
  __shared__ float red[4];
  if ((t & 63) == 0) red[t >> 6] = ss;
  __syncthreads();
  float tot = red[0] + red[1] + red[2] + red[3];
  float sc = rsqrtf(tot * (1.0f / 1024.0f) + eps);
  if (MIX) ((float4*)(XMout + base))[t] = v;
  ushort4 hv;
  hv.x = f2bf(v.x * sc); hv.y = f2bf(v.y * sc);
  hv.z = f2bf(v.z * sc); hv.w = f2bf(v.w * sc);
  ((ushort4*)(Hout + base))[t] = hv;
}

// ---------- RMSNorm of memory/denom -> bf16 m ----------
__global__ __launch_bounds__(256) void k_rms_mem(const float* __restrict__ Mem,
                                                 u16* __restrict__ Mout) {
  const int row = blockIdx.x, t = threadIdx.x;
  const float inv = 1.0f / (float)((row & 4095) + 1);   // S = 4096
  const size_t base = (size_t)row * 1024;
  float4 v = ((const float4*)(Mem + base))[t];
  v.x *= inv; v.y *= inv; v.z *= inv; v.w *= inv;
  float ss = v.x * v.x + v.y * v.y + v.z * v.z + v.w * v.w;
#pragma unroll
  for (int o = 32; o > 0; o >>= 1) ss += __shfl_xor(ss, o);
  __shared__ float red[4];
  if ((t & 63) == 0) red[t >> 6] = ss;
  __syncthreads();
  float tot = red[0] + red[1] + red[2] + red[3];
  float sc = rsqrtf(tot * (1.0f / 1024.0f) + 1.1920929e-7f);
  ushort4 hv;
  hv.x = f2bf(v.x * sc); hv.y = f2bf(v.y * sc);
  hv.z = f2bf(v.z * sc); hv.w = f2bf(v.w * sc);
  ((ushort4*)(Mout + base))[t] = hv;
}

// ---------- chunked scan over S ----------
__global__ __launch_bounds__(256) void k_scan1(const float* __restrict__ P,
                                               float* __restrict__ CS) {
  int blk = blockIdx.x;
  int kt = blk & 3, chunk = (blk >> 2) & 15, b = blk >> 6;
  int k = kt * 256 + threadIdx.x;
  const float* p = P + ((size_t)b * 4096 + (size_t)chunk * 256) * 1024 + k;
  float s = 0.f;
#pragma unroll 8
  for (int i = 0; i < 256; ++i) s += p[(size_t)i * 1024];
  CS[((size_t)b * 16 + chunk) * 1024 + k] = s;
}

__global__ __launch_bounds__(256) void k_scan2(float* __restrict__ CS) {
  int idx = blockIdx.x * 256 + threadIdx.x;  // 4096 columns
  int b = idx >> 10, k = idx & 1023;
  float run = 0.f;
  for (int c = 0; c < 16; ++c) {
    size_t o = ((size_t)b * 16 + c) * 1024 + k;
    float v = CS[o];
    CS[o] = run;       // exclusive prefix
    run += v;
  }
}

__global__ __launch_bounds__(256) void k_scan3(float* __restrict__ P,
                                               const float* __restrict__ CS) {
  int blk = blockIdx.x;
  int kt = blk & 3, chunk = (blk >> 2) & 15, b = blk >> 6;
  int k = kt * 256 + threadIdx.x;
  float run = CS[((size_t)b * 16 + chunk) * 1024 + k];
  float* p = P + ((size_t)b * 4096 + (size_t)chunk * 256) * 1024 + k;
#pragma unroll 8
  for (int i = 0; i < 256; ++i) {
    run += p[(size_t)i * 1024];
    p[(size_t)i * 1024] = run;   // in-place: P becomes memory
  }
}

// ---------- dual-B GEMM: P = sigmoid(A@Wg^T) * (A@Wu^T) ----------
// BM=128, BN=64 (per B matrix), BK=64. 4 waves, each 32x64.
__global__ __launch_bounds__(256, 2) void gemm_dual(
    const u16* __restrict__ A, const u16* __restrict__ Bu,
    const u16* __restrict__ Bg, float* __restrict__ P, int K) {
  __shared__ __align__(16) u16 As[128 * 64];
  __shared__ __align__(16) u16 Us[64 * 64];
  __shared__ __align__(16) u16 Gs[64 * 64];
  const int t = threadIdx.x;
  const int lane = t & 63, wid = t >> 6;
  int bx, by;
  xcd_swz(bx, by);
  const int m0 = by * 128, n0 = bx * 64;
  const int wm = wid * 32;
  const int l15 = lane & 15, lhi = lane >> 4;

  size_t gA[4], gU[2];
#pragma unroll
  for (int i = 0; i < 4; ++i) {
    int j = i * 256 + t;
    int row = j >> 3;
    int k16 = (j & 7) ^ (row & 7);
    gA[i] = (size_t)(m0 + row) * K + k16 * 8;
  }
#pragma unroll
  for (int i = 0; i < 2; ++i) {
    int j = i * 256 + t;
    int row = j >> 3;
    int k16 = (j & 7) ^ (row & 7);
    gU[i] = (size_t)(n0 + row) * K + k16 * 8;
  }

  f32x4 au[2][4], ag[2][4];
#pragma unroll
  for (int mi = 0; mi < 2; ++mi)
#pragma unroll
    for (int ni = 0; ni < 4; ++ni) { au[mi][ni] = 0.0f; ag[mi][ni] = 0.0f; }

  for (int kb = 0; kb < K; kb += 64) {
#pragma unroll
    for (int i = 0; i < 4; ++i) {
      int j = i * 256 + t;
      gll16(A + gA[i] + kb, &As[j * 8]);
    }
#pragma unroll
    for (int i = 0; i < 2; ++i) {
      int j = i * 256 + t;
      gll16(Bu + gU[i] + kb, &Us[j * 8]);
      gll16(Bg + gU[i] + kb, &Gs[j * 8]);
    }
    __syncthreads();
#pragma unroll
    for (int kc = 0; kc < 2; ++kc) {
      s16x8 af[2], uf[4], gf[4];
#pragma unroll
      for (int mi = 0; mi < 2; ++mi) {
        int row = wm + mi * 16 + l15;
        int k16 = (kc * 4 + lhi) ^ (row & 7);
        af[mi] = *(const s16x8*)&As[row * 64 + k16 * 8];
      }
#pragma unroll
      for (int ni = 0; ni < 4; ++ni) {
        int row = ni * 16 + l15;
        int k16 = (kc * 4 + lhi) ^ (row & 7);
        uf[ni] = *(const s16x8*)&Us[row * 64 + k16 * 8];
        gf[ni] = *(const s16x8*)&Gs[row * 64 + k16 * 8];
      }
#pragma unroll
      for (int mi = 0; mi < 2; ++mi)
#pragma unroll
        for (int ni = 0; ni < 4; ++ni) {
          au[mi][ni] = __builtin_amdgcn_mfma_f32_16x16x32_bf16(
              af[mi], uf[ni], au[mi][ni], 0, 0, 0);
          ag[mi][ni] = __builtin_amdgcn_mfma_f32_16x16x32_bf16(
              af[mi], gf[ni], ag[mi][ni], 0, 0, 0);
        }
    }
    __syncthreads();
  }

#pragma unroll
  for (int mi = 0; mi < 2; ++mi) {
    int r0 = m0 + wm + mi * 16 + lhi * 4;
#pragma unroll
    for (int ni = 0; ni < 4; ++ni) {
      int c = n0 + ni * 16 + l15;
#pragma unroll
      for (int j = 0; j < 4; ++j) {
        float u = au[mi][ni][j], g = ag[mi][ni][j];
        P[(size_t)(r0 + j) * 1024 + c] = u / (1.0f + __expf(-g));
      }
    }
  }
}

// ---------- bf16 MFMA GEMM: C[M,N](+ldc) = A[M,K](lda) @ B[N,K](ldb)^T ----------
// EPI 1: Cout(f32) = Cadd + colscale[c]*acc    (in-place Cadd==Cout ok)
// EPI 2: Cout(bf16) = relu(acc)^2
template <int EPI>
__global__ __launch_bounds__(256, 2) void gemm_bf16(
    const u16* __restrict__ A, const u16* __restrict__ Bw, void* __restrict__ Cout,
    const float* __restrict__ Cadd, const float* __restrict__ colscale,
    int K, int lda, int ldb, int ldc) {
  __shared__ __align__(16) u16 As[128 * 64];
  __shared__ __align__(16) u16 Bs[128 * 64];
  const int t = threadIdx.x;
  const int lane = t & 63, wid = t >> 6;
  int bx, by;
  xcd_swz(bx, by);
  const int m0 = by * 128, n0 = bx * 128;
  const int wm = (wid >> 1) * 64, wn = (wid & 1) * 64;
  const int l15 = lane & 15, lhi = lane >> 4;

  size_t gA[4], gB[4];
#pragma unroll
  for (int i = 0; i < 4; ++i) {
    int j = i * 256 + t;
    int row = j >> 3;
    int k16 = (j & 7) ^ (row & 7);
    gA[i] = (size_t)(m0 + row) * lda + k16 * 8;
    gB[i] = (size_t)(n0 + row) * ldb + k16 * 8;
  }

  f32x4 acc[4][4];
#pragma unroll
  for (int mi = 0; mi < 4; ++mi)
#pragma unroll
    for (int ni = 0; ni < 4; ++ni) acc[mi][ni] = 0.0f;

  for (int kb = 0; kb < K; kb += 64) {
#pragma unroll
    for (int i = 0; i < 4; ++i) {
      int j = i * 256 + t;
      gll16(A + gA[i] + kb, &As[j * 8]);
      gll16(Bw + gB[i] + kb, &Bs[j * 8]);
    }
    __syncthreads();
#pragma unroll
    for (int kc = 0; kc < 2; ++kc) {
      s16x8 af[4], bfr[4];
#pragma unroll
      for (int mi = 0; mi < 4; ++mi) {
        int row = wm + mi * 16 + l15;
        int k16 = (kc * 4 + lhi) ^ (row & 7);
        af[mi] = *(const s16x8*)&As[row * 64 + k16 * 8];
      }
#pragma unroll
      for (int ni = 0; ni < 4; ++ni) {
        int row = wn + ni * 16 + l15;
        int k16 = (kc * 4 + lhi) ^ (row & 7);
        bfr[ni] = *(const s16x8*)&Bs[row * 64 + k16 * 8];
      }
#pragma unroll
      for (int mi = 0; mi < 4; ++mi)
#pragma unroll
        for (int ni = 0; ni < 4; ++ni)
          acc[mi][ni] = __builtin_amdgcn_mfma_f32_16x16x32_bf16(
              af[mi], bfr[ni], acc[mi][ni], 0, 0, 0);
    }
    __syncthreads();
  }

#pragma unroll
  for (int mi = 0; mi < 4; ++mi) {
    int r0 = m0 + wm + mi * 16 + lhi * 4;
#pragma unroll
    for (int ni = 0; ni < 4; ++ni) {
      int c = n0 + wn + ni * 16 + l15;
      float cs = (EPI == 1) ? colscale[c] : 0.f;
#pragma unroll
      for (int j = 0; j < 4; ++j) {
        size_t idx = (size_t)(r0 + j) * ldc + c;
        float v = acc[mi][ni][j];
        if (EPI == 1) {
          ((float*)Cout)[idx] = Cadd[idx] + cs * v;
        } else {
          float rv = fmaxf(v, 0.f);
          ((u16*)Cout)[idx] = f2bf(rv * rv);
        }
      }
    }
  }
}

// ---------- launch ----------
extern "C" void kernel_launch(void* const* d_in, const int* in_sizes, int n_in,
                              void* d_out, int out_size, void* d_ws, size_t ws_size,
                              hipStream_t stream) {
  const float* x = (const float*)d_in[0];
  const float* x0 = (const float*)d_in[1];
  const float* Wu = (const float*)d_in[2];
  const float* Wg = (const float*)d_in[3];
  const float* Wo = (const float*)d_in[4];
  const float* Wfc = (const float*)d_in[5];
  const float* Wpj = (const float*)d_in[6];
  const float* mmix = (const float*)d_in[7];
  const float* mscale = (const float*)d_in[8];
  const float* rmix = (const float*)d_in[9];
  float* out = (float*)d_out;

  const int M = 16384;  // B*S

  // workspace layout (~150.25 MB)
  char* ws = (char*)d_ws;
  u16* WuB = (u16*)ws;   ws += (size_t)1024 * 1024 * 2;
  u16* WgB = (u16*)ws;   ws += (size_t)1024 * 1024 * 2;
  u16* WoB = (u16*)ws;   ws += (size_t)1024 * 1024 * 2;
  u16* WfcB = (u16*)ws;  ws += (size_t)4096 * 1024 * 2;
  u16* WpjB = (u16*)ws;  ws += (size_t)1024 * 4096 * 2;
  u16* h = (u16*)ws;     ws += (size_t)M * 1024 * 2;       // h then h2
  float* P = (float*)ws; u16* R2 = (u16*)P;                // R2 reuses dead P/CS/mB
  ws += (size_t)M * 1024 * 4;                              // P (p -> memory)
  float* CS = (float*)ws; ws += (size_t)4 * 16 * 1024 * 4; // chunk sums
  u16* mB = (u16*)ws;     ws += (size_t)M * 1024 * 2;      // normalized memory
  float* xm = out;                                          // xm/x2 lives in d_out

  // weights -> bf16
  k_f2b<<<1024, 256, 0, stream>>>(Wu, WuB, 1024 * 1024);
  k_f2b<<<1024, 256, 0, stream>>>(Wg, WgB, 1024 * 1024);
  k_f2b<<<1024, 256, 0, stream>>>(Wo, WoB, 1024 * 1024);
  k_f2b<<<4096, 256, 0, stream>>>(Wfc, WfcB, 4096 * 1024);
  k_f2b<<<4096, 256, 0, stream>>>(Wpj, WpjB, 4096 * 1024);

  // residual mix + rmsnorm: xm (=out), h
  k_rms<true><<<M, 256, 0, stream>>>(x, x0, rmix, xm, h, 1e-6f);

  // p = sigmoid(h@Wg^T) * (h@Wu^T)
  gemm_dual<<<dim3(16, 128), 256, 0, stream>>>(h, WuB, WgB, P, 1024);

  // memory = cumsum_S(p)  (3-phase chunked scan, in-place)
  k_scan1<<<256, 256, 0, stream>>>(P, CS);
  k_scan2<<<16, 256, 0, stream>>>(CS);
  k_scan3<<<256, 256, 0, stream>>>(P, CS);

  // m = bf16(rmsnorm(memory/denom))
  k_rms_mem<<<M, 256, 0, stream>>>(P, mB);

  // x2 = xm + mmix * (m @ Wo^T)   (in-place in d_out)
  gemm_bf16<1><<<dim3(8, 128), 256, 0, stream>>>(mB, WoB, xm, xm, mmix,
                                                 1024, 1024, 1024, 1024);
  // h2 = bf16(rmsnorm(x2))
  k_rms<false><<<M, 256, 0, stream>>>(xm, nullptr, nullptr, nullptr, h, 1e-6f);

  // MLP in two HID halves; R2 buffer (M x 2048 bf16) reused
  for (int c = 0; c < 2; ++c) {
    gemm_bf16<2><<<dim3(16, 128), 256, 0, stream>>>(
        h, WfcB + (size_t)c * 2048 * 1024, R2, nullptr, nullptr,
        1024, 1024, 1024, 2048);
    gemm_bf16<1><<<dim3(8, 128), 256, 0, stream>>>(
        R2, WpjB + (size_t)c * 2048, out, out, mscale,
        2048, 2048, 4096, 1024);
  }
}